// Round 9
// baseline (169.601 us; speedup 1.0000x reference)
//
#include <hip/hip_runtime.h>
#include <math.h>

#define BB 16
#define QQ 900
#define CC 92
#define NP 32
#define TT (BB*NP)     // 512
#define RSTRIDE 1024   // LDS cost row stride (floats): 64 lanes x 16 cols
#define SENT (-1e30f)  // used / out-of-range sentinel in the f32 v-copy
#define EPS_CAND 1e-4f // f32-vs-f64 key error bound (~8e-6) with 13x margin

// ---------------------------------------------------------------------------
__device__ __forceinline__ double mkdbl(int lo, int hi) {
    return __longlong_as_double(((long long)hi << 32) | (unsigned int)lo);
}
__device__ __forceinline__ double readlane_dbl(double x, int s) {
    long long l = __double_as_longlong(x);
    int lo = __builtin_amdgcn_readlane((int)l, s);
    int hi = __builtin_amdgcn_readlane((int)(l >> 32), s);
    return mkdbl(lo, hi);
}

// fp64 DPP min step (2 dpp movs + v_min_f64); row_shr:1/2/4/8 + row_bcast:15/31
// leaves the global min in lane 63 (HW-verified rounds 5-8, absmax=0).
#define DPP_MIN64(CTRL)                                                       \
    {                                                                         \
        long long _l = __double_as_longlong(m);                               \
        int _lo = (int)_l, _hi = (int)(_l >> 32);                             \
        int _olo = __builtin_amdgcn_update_dpp(_lo, _lo, CTRL, 0xf, 0xf, false); \
        int _ohi = __builtin_amdgcn_update_dpp(_hi, _hi, CTRL, 0xf, 0xf, false); \
        m = fmin(m, mkdbl(_olo, _ohi));                                       \
    }
// fp32 DPP min step (1 dpp mov + v_min_f32), same lane pattern.
#define DPP_MIN32(CTRL)                                                       \
    {                                                                         \
        int _b = __float_as_int(mf);                                          \
        int _o = __builtin_amdgcn_update_dpp(_b, _b, CTRL, 0xf, 0xf, false);  \
        mf = fminf(mf, __int_as_float(_o));                                   \
    }

// Dynamic LDS partition (bytes)
#define OFF_COST 0
#define SZ_COST  (NP * RSTRIDE * 4)        // 131072
#define OFF_U    (OFF_COST + SZ_COST)      // 33 dbl  -> 264
#define OFF_V    (OFF_U + 264)             // 901 dbl -> 7208
#define OFF_P    (OFF_V + 7208)            // 901 int -> 3604
#define OFF_MAX  (OFF_P + 3604)            // 900 f   -> 3600
#define OFF_SUM  (OFF_MAX + 3600)          // 900 f   -> 3600
#define DYN_BYTES (OFF_SUM + 3600)         // 149348  (< 160 KiB)

// ---------------------------------------------------------------------------
// One block per batch b, 256 threads. Waves 0-3: softmax + cost build into
// LDS; wave 0 alone: the serial reference-_lsa walk; all: float4 epilogue.
//
// Exact reference semantics (established rounds 2-8, absmax=0):
//  * mv == cur algebraically -> argmin over unused j of key(c - v0[j]).
//  * FAST PATH: f32 keys; if exactly ONE candidate lies within EPS_CAND of
//    the f32 min (EPS >= 2x max f32-key error), it equals the f64 argmin.
//    Otherwise EXACT fp64 packed-key fallback (col in low 11 bits = exact
//    first-occurrence tie-break), v0 re-read from s_v (frozen in-phase).
//  * deltas recomputed at phase end in EXACT ref order ((c - u0) - v0);
//    u/v replayed with the reference's left-associated per-iteration order.
__launch_bounds__(256)
__global__ void matcher_kernel(const float* __restrict__ logits,   // (B,Q,C)
                               const float* __restrict__ pboxes,   // (B,Q,4)
                               const int*   __restrict__ labels,   // (T,)
                               const float* __restrict__ tboxes,   // (T,4)
                               float* __restrict__ out)            // (Q,T)
{
    extern __shared__ char smem[];
    float*           s_cost = (float*)(smem + OFF_COST);   // [NP][RSTRIDE]
    volatile double* s_u    = (volatile double*)(smem + OFF_U);
    volatile double* s_v    = (volatile double*)(smem + OFF_V);
    volatile int*    s_p    = (volatile int*)(smem + OFF_P);
    float*           s_max  = (float*)(smem + OFF_MAX);
    float*           s_sum  = (float*)(smem + OFF_SUM);

    const int b   = blockIdx.x;
    const int tid = threadIdx.x;

    // ---- softmax denominators (FP order = rounds 3-8) ---------------------
    const float* lg = logits + (size_t)b * QQ * CC;
    for (int q = tid; q < QQ; q += 256) {
        const float4* row4 = (const float4*)(lg + q * CC);   // 92 = 23 float4
        float mx = -INFINITY;
        #pragma unroll
        for (int k = 0; k < 23; ++k) {
            float4 x = row4[k];
            mx = fmaxf(mx, x.x); mx = fmaxf(mx, x.y);
            mx = fmaxf(mx, x.z); mx = fmaxf(mx, x.w);
        }
        float s = 0.f;
        #pragma unroll
        for (int k = 0; k < 23; ++k) {
            float4 x = row4[k];
            s += expf(x.x - mx); s += expf(x.y - mx);
            s += expf(x.z - mx); s += expf(x.w - mx);
        }
        s_max[q] = mx;
        s_sum[q] = s;
    }
    for (int j = tid; j <= QQ; j += 256) { s_p[j] = 0; s_v[j] = 0.0; }
    if (tid <= NP) s_u[tid] = 0.0;
    __syncthreads();

    // ---- cost matrix -> LDS (FP order identical to rounds 2-8) ------------
    const float* pb = pboxes + (size_t)b * QQ * 4;
    const float* tb = tboxes + (size_t)b * NP * 4;
    const int*   lb = labels + b * NP;
    for (int e = tid; e < NP * QQ; e += 256) {
        int t = e / QQ;
        int q = e - t * QQ;
        float l    = lg[q * CC + lb[t]];
        float prob = expf(l - s_max[q]) / s_sum[q];
        float cclass = -prob;
        float p0 = pb[q*4+0], p1 = pb[q*4+1], p2 = pb[q*4+2], p3 = pb[q*4+3];
        float t0 = tb[t*4+0], t1 = tb[t*4+1], t2 = tb[t*4+2], t3 = tb[t*4+3];
        float cbbox = fabsf(p0-t0) + fabsf(p1-t1) + fabsf(p2-t2) + fabsf(p3-t3);
        float px1 = p0 - 0.5f*p2, py1 = p1 - 0.5f*p3;
        float px2 = p0 + 0.5f*p2, py2 = p1 + 0.5f*p3;
        float tx1 = t0 - 0.5f*t2, ty1 = t1 - 0.5f*t3;
        float tx2 = t0 + 0.5f*t2, ty2 = t1 + 0.5f*t3;
        float area1 = (px2-px1)*(py2-py1);
        float area2 = (tx2-tx1)*(ty2-ty1);
        float ltx = fmaxf(px1,tx1), lty = fmaxf(py1,ty1);
        float rbx = fminf(px2,tx2), rby = fminf(py2,ty2);
        float wx = fmaxf(rbx-ltx, 0.f), wy = fmaxf(rby-lty, 0.f);
        float inter = wx*wy;
        float uni = area1 + area2 - inter;
        float iou = inter / uni;
        float cx1 = fminf(px1,tx1), cy1 = fminf(py1,ty1);
        float cx2 = fmaxf(px2,tx2), cy2 = fmaxf(py2,ty2);
        float cwx = fmaxf(cx2-cx1, 0.f), cwy = fmaxf(cy2-cy1, 0.f);
        float areac = cwx*cwy;
        float giou = iou - (areac - uni) / areac;
        s_cost[t * RSTRIDE + q] = 5.f*cbbox + 1.f*cclass + 2.f*(-giou);
    }
    for (int e = tid; e < NP * (RSTRIDE - QQ); e += 256) {
        int row = e / (RSTRIDE - QQ);
        int c   = e - row * (RSTRIDE - QQ);
        s_cost[row * RSTRIDE + QQ + c] = 0.f;
    }
    __syncthreads();

    // ---- the serial walk: WAVE 0 ONLY, barrier-free -----------------------
    if (tid < 64) {
        const int lane = tid;
        int acol = 0;                       // lane r-1: column assigned to row r

        for (int i = 1; i <= NP; ++i) {
            // per-phase frozen f32 copy of v (SENT marks used/out-of-range)
            float wf[16];
            #pragma unroll
            for (int k = 0; k < 16; ++k) {
                int col = 4 * lane + ((k >> 2) << 8) + (k & 3) + 1;
                wf[k] = (col <= QQ) ? (float)s_v[col] : SENT;
            }

            int i0 = i, j1prev = 0, T = 0;
            int path_reg = 1, row_reg = 1;

            for (int t = 1; t <= NP + 1; ++t) {
                // mark previous winner used (f32 cndmask, static unroll)
                if (j1prev) {
                    #pragma unroll
                    for (int k = 0; k < 16; ++k) {
                        int col = 4 * lane + ((k >> 2) << 8) + (k & 3) + 1;
                        if (col == j1prev) wf[k] = SENT;
                    }
                }
                if (lane == t) row_reg = i0;      // writelane (i0 uniform)

                // 4x ds_read_b128 of the cost row
                const float4* crow4 = (const float4*)(s_cost + (i0 - 1) * RSTRIDE);
                float4 cf[4];
                #pragma unroll
                for (int k = 0; k < 4; ++k) cf[k] = crow4[lane + (k << 6)];
                float cfk[16];
                #pragma unroll
                for (int k = 0; k < 4; ++k) {
                    cfk[4*k+0] = cf[k].x; cfk[4*k+1] = cf[k].y;
                    cfk[4*k+2] = cf[k].z; cfk[4*k+3] = cf[k].w;
                }

                // ---- FAST PATH: f32 keys, value-only min -----------------
                float kf[16];
                #pragma unroll
                for (int k = 0; k < 16; ++k) kf[k] = cfk[k] - wf[k];

                float mf = fminf(fminf(fminf(fminf(kf[0], kf[1]), kf[2]),
                                 fminf(fminf(kf[3], kf[4]), kf[5])),
                                 fminf(fminf(fminf(kf[6], kf[7]), kf[8]),
                                 fminf(fminf(kf[9], kf[10]), kf[11])));
                mf = fminf(mf, fminf(fminf(kf[12], kf[13]), fminf(kf[14], kf[15])));

                DPP_MIN32(0x111);  // row_shr:1
                DPP_MIN32(0x112);  // row_shr:2
                DPP_MIN32(0x114);  // row_shr:4
                DPP_MIN32(0x118);  // row_shr:8
                DPP_MIN32(0x142);  // row_bcast:15
                DPP_MIN32(0x143);  // row_bcast:31
                const float m1g = __int_as_float(
                    __builtin_amdgcn_readlane(__float_as_int(mf), 63));
                const float thr = m1g + EPS_CAND;

                unsigned msk = 0;
                #pragma unroll
                for (int k = 0; k < 16; ++k)
                    if (kf[k] <= thr) msk |= 1u << k;

                unsigned long long lm = __ballot(msk != 0);
                int j1 = -1;
                if (__popcll(lm) == 1) {
                    int L  = (int)__builtin_ctzll(lm);
                    int mL = __builtin_amdgcn_readlane((int)msk, L);
                    if ((mL & (mL - 1)) == 0) {
                        int kk = __builtin_ctz((unsigned)mL);
                        j1 = 4 * L + ((kk >> 2) << 8) + (kk & 3) + 1;
                    }
                }
                if (j1 < 0) {
                    // ---- EXACT fp64 fallback (rare) ----------------------
                    // v0 from s_v (frozen in-phase); used via wf sentinel;
                    // col in low 11 bits = exact first-occurrence tie-break.
                    double key[16];
                    #pragma unroll
                    for (int k = 0; k < 16; ++k) {
                        int col = 4 * lane + ((k >> 2) << 8) + (k & 3) + 1;
                        bool dead = (col > QQ) || (wf[k] == SENT);
                        double v0 = dead ? -1e30 : (double)s_v[col];
                        double d  = (double)cfk[k] - v0;
                        long long bits =
                            (__double_as_longlong(d) & ~2047LL) | (long long)col;
                        key[k] = __longlong_as_double(bits);
                    }
                    double a0 = fmin(key[0], key[1]),   a1 = fmin(key[2], key[3]);
                    double a2 = fmin(key[4], key[5]),   a3 = fmin(key[6], key[7]);
                    double a4 = fmin(key[8], key[9]),   a5 = fmin(key[10], key[11]);
                    double a6 = fmin(key[12], key[13]), a7 = fmin(key[14], key[15]);
                    double b0 = fmin(a0, a1), b1 = fmin(a2, a3);
                    double b2 = fmin(a4, a5), b3 = fmin(a6, a7);
                    double m  = fmin(fmin(b0, b1), fmin(b2, b3));
                    DPP_MIN64(0x111);
                    DPP_MIN64(0x112);
                    DPP_MIN64(0x114);
                    DPP_MIN64(0x118);
                    DPP_MIN64(0x142);
                    DPP_MIN64(0x143);
                    int wlo = __builtin_amdgcn_readlane(
                        (int)__double_as_longlong(m), 63);
                    j1 = wlo & 2047;
                }

                if (lane == t) path_reg = j1;     // writelane (j1 uniform)

                // p[j1] via ballot over register-resident assignment map
                unsigned long long mask = __ballot(acol == j1);
                if (mask == 0) { T = t; break; }
                i0 = (int)__builtin_ctzll(mask) + 1;
                j1prev = j1;
            }

            // ---- phase end: exact ordered replay (lanes 1..T hold r_t, j_t)
            const int  rt  = row_reg;
            const int  myj = path_reg;
            const bool act = (lane >= 1 && lane <= T);
            double mydelta = 0.0, uu = 0.0, vv = 0.0;
            if (act) {
                double cD = (double)s_cost[(rt - 1) * RSTRIDE + (myj - 1)];
                mydelta = (cD - s_u[rt]) - s_v[myj];   // exact ref op order
                uu = s_u[rt];
                vv = s_v[myj];
            }
            for (int s = 1; s <= T; ++s) {
                double ds = readlane_dbl(mydelta, s);
                int    js = __builtin_amdgcn_readlane(path_reg, s);
                int    rs = __builtin_amdgcn_readlane(row_reg, s);
                if (lane >= 1 && lane <= s) uu += ds;   // u[r_t] += d_t..d_T
                if (lane >= 1 && lane <  s) vv -= ds;   // v[j_t] -= d_{t+1}..d_T
                if (rs == lane + 1) acol = js;          // row r_s now on col j_s
            }
            if (act) {
                s_u[rt]  = uu;
                s_v[myj] = vv;
                s_p[myj] = rt;
            }
        }
    }
    __syncthreads();

    // ---- epilogue: full (900 x 32) tile, float4 stores --------------------
    for (int e = tid; e < QQ * 8; e += 256) {
        int q = e >> 3;
        int f = e & 7;
        int pq = s_p[q + 1];
        int base = 4 * f;
        float4 o;
        o.x = (pq == base + 1) ? 1.f : 0.f;
        o.y = (pq == base + 2) ? 1.f : 0.f;
        o.z = (pq == base + 3) ? 1.f : 0.f;
        o.w = (pq == base + 4) ? 1.f : 0.f;
        ((float4*)(out + (size_t)q * TT + b * NP))[f] = o;
    }
}

// ---------------------------------------------------------------------------
extern "C" void kernel_launch(void* const* d_in, const int* in_sizes, int n_in,
                              void* d_out, int out_size, void* d_ws, size_t ws_size,
                              hipStream_t stream) {
    const float* logits = (const float*)d_in[0];   // (16,900,92)
    const float* pboxes = (const float*)d_in[1];   // (16,900,4)
    const int*   labels = (const int*)  d_in[2];   // (512,)
    const float* tboxes = (const float*)d_in[3];   // (512,4)
    float* out = (float*)d_out;                    // (900,512) fp32

    (void)hipFuncSetAttribute((const void*)matcher_kernel,
                              hipFuncAttributeMaxDynamicSharedMemorySize,
                              DYN_BYTES);

    matcher_kernel<<<BB, 256, DYN_BYTES, stream>>>(logits, pboxes, labels,
                                                   tboxes, out);
}

// Round 10
// 168.527 us; speedup vs baseline: 1.0064x; 1.0064x over previous
//
#include <hip/hip_runtime.h>
#include <math.h>

#define BB 16
#define QQ 900
#define CC 92
#define NP 32
#define TT (BB*NP)     // 512
#define RSTRIDE 1024   // LDS cost row stride (floats): 64 lanes x 16 cols

// ---------------------------------------------------------------------------
__device__ __forceinline__ double mkdbl(int lo, int hi) {
    return __longlong_as_double(((long long)hi << 32) | (unsigned int)lo);
}
__device__ __forceinline__ double readlane_dbl(double x, int s) {
    long long l = __double_as_longlong(x);
    int lo = __builtin_amdgcn_readlane((int)l, s);
    int hi = __builtin_amdgcn_readlane((int)(l >> 32), s);
    return mkdbl(lo, hi);
}

// fp64 DPP min step (2 dpp movs + v_min_f64); row_shr:1/2/4/8 + row_bcast:15/31
// leaves the global min in lane 63 (HW-verified rounds 5-9, absmax=0).
#define DPP_MIN64(CTRL)                                                       \
    {                                                                         \
        long long _l = __double_as_longlong(m);                               \
        int _lo = (int)_l, _hi = (int)(_l >> 32);                             \
        int _olo = __builtin_amdgcn_update_dpp(_lo, _lo, CTRL, 0xf, 0xf, false); \
        int _ohi = __builtin_amdgcn_update_dpp(_hi, _hi, CTRL, 0xf, 0xf, false); \
        m = fmin(m, mkdbl(_olo, _ohi));                                       \
    }

// Dynamic LDS partition (bytes)
#define OFF_COST 0
#define SZ_COST  (NP * RSTRIDE * 4)        // 131072
#define OFF_U    (OFF_COST + SZ_COST)      // 33 dbl  -> 264
#define OFF_V    (OFF_U + 264)             // 901 dbl -> 7208
#define OFF_P    (OFF_V + 7208)            // 901 int -> 3604
#define OFF_MAX  (OFF_P + 3604)            // 900 f   -> 3600
#define OFF_SUM  (OFF_MAX + 3600)          // 900 f   -> 3600
#define DYN_BYTES (OFF_SUM + 3600)         // 149348  (< 160 KiB)

// ---------------------------------------------------------------------------
// One block per batch b, 256 threads. Waves 0-3: softmax + cost build into
// LDS; wave 0 alone: the serial reference-_lsa walk; all: float4 epilogue.
//
// Exact reference semantics (established rounds 2-9, absmax=0):
//  * mv == cur algebraically (minv stays ~1e18) -> argmin over unused j of
//    (c - u0) - v0[j] == argmin of key(c - v0[j]); col packed into the key's
//    low 11 bits implements first-occurrence tie-break exactly (perturbation
//    ~1e-11 << key gaps).
//  * deltas recomputed at phase end in EXACT ref order ((c - u0) - v0);
//    u/v replayed with the reference's left-associated per-iteration order.
//
// Round-10 change: next-row ds_read_b128s are issued IMMEDIATELY after the
// ballot/ctz resolves i0 (loop bottom), so the w-marking cndmasks and
// bookkeeping of the next iteration overlap the ~140-cycle LDS latency.
__launch_bounds__(256)
__global__ void matcher_kernel(const float* __restrict__ logits,   // (B,Q,C)
                               const float* __restrict__ pboxes,   // (B,Q,4)
                               const int*   __restrict__ labels,   // (T,)
                               const float* __restrict__ tboxes,   // (T,4)
                               float* __restrict__ out)            // (Q,T)
{
    extern __shared__ char smem[];
    float*           s_cost = (float*)(smem + OFF_COST);   // [NP][RSTRIDE]
    volatile double* s_u    = (volatile double*)(smem + OFF_U);
    volatile double* s_v    = (volatile double*)(smem + OFF_V);
    volatile int*    s_p    = (volatile int*)(smem + OFF_P);
    float*           s_max  = (float*)(smem + OFF_MAX);
    float*           s_sum  = (float*)(smem + OFF_SUM);

    const int b   = blockIdx.x;
    const int tid = threadIdx.x;

    // ---- softmax denominators (FP order = rounds 3-9) ---------------------
    const float* lg = logits + (size_t)b * QQ * CC;
    for (int q = tid; q < QQ; q += 256) {
        const float4* row4 = (const float4*)(lg + q * CC);   // 92 = 23 float4
        float mx = -INFINITY;
        #pragma unroll
        for (int k = 0; k < 23; ++k) {
            float4 x = row4[k];
            mx = fmaxf(mx, x.x); mx = fmaxf(mx, x.y);
            mx = fmaxf(mx, x.z); mx = fmaxf(mx, x.w);
        }
        float s = 0.f;
        #pragma unroll
        for (int k = 0; k < 23; ++k) {
            float4 x = row4[k];
            s += expf(x.x - mx); s += expf(x.y - mx);
            s += expf(x.z - mx); s += expf(x.w - mx);
        }
        s_max[q] = mx;
        s_sum[q] = s;
    }
    for (int j = tid; j <= QQ; j += 256) { s_p[j] = 0; s_v[j] = 0.0; }
    if (tid <= NP) s_u[tid] = 0.0;
    __syncthreads();

    // ---- cost matrix -> LDS (FP order identical to rounds 2-9) ------------
    const float* pb = pboxes + (size_t)b * QQ * 4;
    const float* tb = tboxes + (size_t)b * NP * 4;
    const int*   lb = labels + b * NP;
    for (int e = tid; e < NP * QQ; e += 256) {
        int t = e / QQ;
        int q = e - t * QQ;
        float l    = lg[q * CC + lb[t]];
        float prob = expf(l - s_max[q]) / s_sum[q];
        float cclass = -prob;
        float p0 = pb[q*4+0], p1 = pb[q*4+1], p2 = pb[q*4+2], p3 = pb[q*4+3];
        float t0 = tb[t*4+0], t1 = tb[t*4+1], t2 = tb[t*4+2], t3 = tb[t*4+3];
        float cbbox = fabsf(p0-t0) + fabsf(p1-t1) + fabsf(p2-t2) + fabsf(p3-t3);
        float px1 = p0 - 0.5f*p2, py1 = p1 - 0.5f*p3;
        float px2 = p0 + 0.5f*p2, py2 = p1 + 0.5f*p3;
        float tx1 = t0 - 0.5f*t2, ty1 = t1 - 0.5f*t3;
        float tx2 = t0 + 0.5f*t2, ty2 = t1 + 0.5f*t3;
        float area1 = (px2-px1)*(py2-py1);
        float area2 = (tx2-tx1)*(ty2-ty1);
        float ltx = fmaxf(px1,tx1), lty = fmaxf(py1,ty1);
        float rbx = fminf(px2,tx2), rby = fminf(py2,ty2);
        float wx = fmaxf(rbx-ltx, 0.f), wy = fmaxf(rby-lty, 0.f);
        float inter = wx*wy;
        float uni = area1 + area2 - inter;
        float iou = inter / uni;
        float cx1 = fminf(px1,tx1), cy1 = fminf(py1,ty1);
        float cx2 = fmaxf(px2,tx2), cy2 = fmaxf(py2,ty2);
        float cwx = fmaxf(cx2-cx1, 0.f), cwy = fmaxf(cy2-cy1, 0.f);
        float areac = cwx*cwy;
        float giou = iou - (areac - uni) / areac;
        s_cost[t * RSTRIDE + q] = 5.f*cbbox + 1.f*cclass + 2.f*(-giou);
    }
    // zero pad columns 900..1023 (NaN guard for unconditional b128 loads)
    for (int e = tid; e < NP * (RSTRIDE - QQ); e += 256) {
        int row = e / (RSTRIDE - QQ);
        int c   = e - row * (RSTRIDE - QQ);
        s_cost[row * RSTRIDE + QQ + c] = 0.f;
    }
    __syncthreads();

    // ---- the serial walk: WAVE 0 ONLY, barrier-free -----------------------
    if (tid < 64) {
        const int lane = tid;
        int acol = 0;                       // lane r-1: column assigned to row r
        const float4* cbase4 = (const float4*)s_cost;  // 256 float4 per row

        for (int i = 1; i <= NP; ++i) {
            // per-phase frozen copy of v (sentinel -1e30 for pads)
            double w[16];
            #pragma unroll
            for (int k = 0; k < 16; ++k) {
                int col = 4 * lane + ((k >> 2) << 8) + (k & 3) + 1;
                w[k] = (col <= QQ) ? s_v[col] : -1e30;
            }

            int i0 = i, j1prev = 0, T = 0;
            int path_reg = 1, row_reg = 1;

            // issue first row's loads before entering the loop
            float4 cf[4];
            {
                const float4* crow4 = cbase4 + (size_t)(i0 - 1) * (RSTRIDE / 4);
                #pragma unroll
                for (int k = 0; k < 4; ++k) cf[k] = crow4[lane + (k << 6)];
            }

            for (int t = 1;; ++t) {
                if (lane == t) row_reg = i0;      // writelane (i0 uniform)
                // mark previous winner used (overlaps in-flight loads)
                if (j1prev) {
                    #pragma unroll
                    for (int k = 0; k < 16; ++k) {
                        int col = 4 * lane + ((k >> 2) << 8) + (k & 3) + 1;
                        if (col == j1prev) w[k] = -1e30;
                    }
                }

                // keys: (c - v0[j]) packed with col in low 11 bits
                double key[16];
                #pragma unroll
                for (int k = 0; k < 4; ++k) {
                    const float* cp = (const float*)&cf[k];
                    #pragma unroll
                    for (int e2 = 0; e2 < 4; ++e2) {
                        int col = 4 * lane + (k << 8) + e2 + 1;
                        double d = (double)cp[e2] - w[4 * k + e2];
                        long long bits =
                            (__double_as_longlong(d) & ~2047LL) | (long long)col;
                        key[4 * k + e2] = __longlong_as_double(bits);
                    }
                }
                // in-lane 16-way min tree (pure v_min_f64)
                double a0 = fmin(key[0], key[1]),   a1 = fmin(key[2], key[3]);
                double a2 = fmin(key[4], key[5]),   a3 = fmin(key[6], key[7]);
                double a4 = fmin(key[8], key[9]),   a5 = fmin(key[10], key[11]);
                double a6 = fmin(key[12], key[13]), a7 = fmin(key[14], key[15]);
                double b0 = fmin(a0, a1), b1 = fmin(a2, a3);
                double b2 = fmin(a4, a5), b3 = fmin(a6, a7);
                double m  = fmin(fmin(b0, b1), fmin(b2, b3));

                DPP_MIN64(0x111);  // row_shr:1
                DPP_MIN64(0x112);  // row_shr:2
                DPP_MIN64(0x114);  // row_shr:4
                DPP_MIN64(0x118);  // row_shr:8
                DPP_MIN64(0x142);  // row_bcast:15
                DPP_MIN64(0x143);  // row_bcast:31

                int wlo = __builtin_amdgcn_readlane((int)__double_as_longlong(m), 63);
                int j1  = wlo & 2047;

                if (lane == t) path_reg = j1;     // writelane (j1 uniform)

                // p[j1] via ballot over register-resident assignment map
                unsigned long long mask = __ballot(acol == j1);
                if (mask == 0) { T = t; break; }
                int L = (int)__builtin_ctzll(mask);
                i0 = L + 1;
                j1prev = j1;

                // EARLY ISSUE: next row's loads, before next iter's marking
                const float4* crow4 = cbase4 + (size_t)L * (RSTRIDE / 4);
                #pragma unroll
                for (int k = 0; k < 4; ++k) cf[k] = crow4[lane + (k << 6)];
            }

            // ---- phase end: exact ordered replay (lanes 1..T hold r_t, j_t)
            const int  rt  = row_reg;
            const int  myj = path_reg;
            const bool act = (lane >= 1 && lane <= T);
            double mydelta = 0.0, uu = 0.0, vv = 0.0;
            if (act) {
                double cD = (double)s_cost[(rt - 1) * RSTRIDE + (myj - 1)];
                mydelta = (cD - s_u[rt]) - s_v[myj];   // exact ref op order
                uu = s_u[rt];
                vv = s_v[myj];
            }
            for (int s = 1; s <= T; ++s) {
                double ds = readlane_dbl(mydelta, s);
                int    js = __builtin_amdgcn_readlane(path_reg, s);
                int    rs = __builtin_amdgcn_readlane(row_reg, s);
                if (lane >= 1 && lane <= s) uu += ds;   // u[r_t] += d_t..d_T
                if (lane >= 1 && lane <  s) vv -= ds;   // v[j_t] -= d_{t+1}..d_T
                if (rs == lane + 1) acol = js;          // row r_s now on col j_s
            }
            if (act) {
                s_u[rt]  = uu;
                s_v[myj] = vv;
                s_p[myj] = rt;
            }
        }
    }
    __syncthreads();

    // ---- epilogue: full (900 x 32) tile, float4 stores --------------------
    for (int e = tid; e < QQ * 8; e += 256) {
        int q = e >> 3;
        int f = e & 7;
        int pq = s_p[q + 1];
        int base = 4 * f;
        float4 o;
        o.x = (pq == base + 1) ? 1.f : 0.f;
        o.y = (pq == base + 2) ? 1.f : 0.f;
        o.z = (pq == base + 3) ? 1.f : 0.f;
        o.w = (pq == base + 4) ? 1.f : 0.f;
        ((float4*)(out + (size_t)q * TT + b * NP))[f] = o;
    }
}

// ---------------------------------------------------------------------------
extern "C" void kernel_launch(void* const* d_in, const int* in_sizes, int n_in,
                              void* d_out, int out_size, void* d_ws, size_t ws_size,
                              hipStream_t stream) {
    const float* logits = (const float*)d_in[0];   // (16,900,92)
    const float* pboxes = (const float*)d_in[1];   // (16,900,4)
    const int*   labels = (const int*)  d_in[2];   // (512,)
    const float* tboxes = (const float*)d_in[3];   // (512,4)
    float* out = (float*)d_out;                    // (900,512) fp32

    (void)hipFuncSetAttribute((const void*)matcher_kernel,
                              hipFuncAttributeMaxDynamicSharedMemorySize,
                              DYN_BYTES);

    matcher_kernel<<<BB, 256, DYN_BYTES, stream>>>(logits, pboxes, labels,
                                                   tboxes, out);
}